// Round 2
// baseline (54.795 us; speedup 1.0000x reference)
//
#include <hip/hip_runtime.h>
#include <math.h>

typedef __attribute__((ext_vector_type(8))) _Float16 f16x8;
typedef __attribute__((ext_vector_type(4))) float f32x4;

#define TSTEPS 23

// ws byte offsets
#define WSB_Z  0        // [64][64] f32 sigmoid LUT (16384 B)
#define WSB_B1 16384    // [64 n][168 k] f16 combined table *256 (21504 B)
#define WSB_W2 37888    // [64 n][72 k] f16 rw2 transposed (9216 B)

__global__ __launch_bounds__(256) void sm_precompute(
    const float* __restrict__ embed, const float* __restrict__ gw1,
    const float* __restrict__ gb1, const float* __restrict__ gw2,
    const float* __restrict__ gb2, const float* __restrict__ rw1,
    const float* __restrict__ rb1, const float* __restrict__ rw2,
    char* __restrict__ wsc)
{
    const int tid = threadIdx.x;
    const int blk = blockIdx.x;
    if (blk < 64) {
        // Z row c — numerically IDENTICAL to the passing round-1 path
        const int c = blk;
        __shared__ float v[64 * 32];
        __shared__ float u[32];
        for (int idx = tid; idx < 2048; idx += 256) {
            const int s = idx >> 5, j = idx & 31;
            float acc = 0.f;
            const float* er = embed + s * 64;
            for (int k = 0; k < 64; ++k)
                acc = fmaf(er[k], gw1[(64 + k) * 32 + j], acc);
            v[idx] = acc;
        }
        if (tid < 32) {
            float acc = 0.f;
            const float* er = embed + c * 64;
            for (int k = 0; k < 64; ++k)
                acc = fmaf(er[k], gw1[k * 32 + tid], acc);
            u[tid] = acc;
        }
        __syncthreads();
        if (tid < 64) {
            double z = (double)gb2[0];
            for (int j = 0; j < 32; ++j) {
                const double a = (double)u[j] + (double)v[tid * 32 + j] + (double)gb1[j];
                if (a > 0.0) z += a * (double)gw2[j];
            }
            ((float*)(wsc + WSB_Z))[c * 64 + tid] = (float)(1.0 / (1.0 + exp(-z)));
        }
    } else if (blk == 64) {
        // combined B table, Bt[n][k], scaled by 256
        _Float16* b1 = (_Float16*)(wsc + WSB_B1);
        for (int e = tid; e < 8320; e += 256) {       // 64 n * 130 k
            const int n = e & 63, k = e >> 6;
            float acc;
            if (k < 64) {                              // R8 token rows (counts side)
                acc = 0.f;
                const float* er = embed + k * 64;
                for (int m = 0; m < 64; ++m)
                    acc = fmaf(er[m], rw1[(64 + m) * 64 + n], acc);
                acc *= 0.125f * 256.f;
            } else {                                   // QP query rows (incl rb1)
                const int t = k - 64;
                acc = rb1[n];
                const float* er = embed + t * 64;
                for (int m = 0; m < 64; ++m)
                    acc = fmaf(er[m], rw1[m * 64 + n], acc);
                acc *= 256.f;
            }
            b1[n * 168 + k] = (_Float16)acc;
        }
        for (int e = tid; e < 2432; e += 256) {        // zero pads k in [130,168)
            const int n = e / 38, k = 130 + (e - n * 38);
            b1[n * 168 + k] = (_Float16)0.f;
        }
    } else {
        // rw2 transposed to Bt[n][j] fp16
        _Float16* w2t = (_Float16*)(wsc + WSB_W2);
        for (int e = tid; e < 4096; e += 256) {
            const int n = e & 63, j = e >> 6;
            w2t[n * 72 + j] = (_Float16)rw2[j * 64 + n];
        }
    }
}

__global__ __launch_bounds__(256, 2) void sm_main(
    const int* __restrict__ seqs, const int* __restrict__ qtok,
    const float* __restrict__ rb2, const char* __restrict__ wsc,
    float* __restrict__ out)
{
    __shared__ __align__(16) float     sZ[64 * 64];
    __shared__ __align__(16) _Float16  sB1[64 * 168];
    __shared__ __align__(16) _Float16  sA[64 * 168];   // reused as sOut f32 [64][68]
    __shared__ __align__(16) _Float16  sW2[64 * 72];
    __shared__ __align__(16) _Float16  sH[64 * 72];
    __shared__ unsigned sTokPk[64 * 6];
    __shared__ float sRb2[64];

    const int tid = threadIdx.x;
    const int base = blockIdx.x * 64;

    // ---- phase 0: stage Z + tokens (all threads) ----
    {
        const float4* zsrc = (const float4*)(wsc + WSB_Z);
        float4* zdst = (float4*)sZ;
        for (int i = tid; i < 1024; i += 256) zdst[i] = zsrc[i];
        const int4* sq = (const int4*)(seqs + base * 24);
        for (int g = tid; g < 384; g += 256) {
            const int4 w = sq[g];
            sTokPk[g] = (unsigned)w.x | ((unsigned)w.y << 8) |
                        ((unsigned)w.z << 16) | ((unsigned)w.w << 24);
        }
        if (tid < 64) sRb2[tid] = rb2[tid];
    }
    int qt = 0;
    if (tid < 64) qt = qtok[base + tid];
    __syncthreads();

    // ---- phase 1: wave0 scans; waves 1-3 stage B1/W2 and zero A ----
    unsigned lo = 0, hi = 0;
    if (tid < 64) {
        const unsigned char* tk = ((const unsigned char*)sTokPk) + tid * 24;
        lo = sTokPk[tid * 6 + 0];
        hi = sTokPk[tid * 6 + 1];
        #pragma unroll
        for (int t = 8; t < TSTEPS; ++t) {
            const int c = tk[t];
            const float* zr = sZ + c * 64;
            float b = zr[lo & 63]; int am = 0; float z;
            z = zr[(lo >> 8) & 63];  if (z > b) { b = z; am = 1; }
            z = zr[(lo >> 16) & 63]; if (z > b) { b = z; am = 2; }
            z = zr[lo >> 24];        if (z > b) { b = z; am = 3; }
            z = zr[hi & 63];         if (z > b) { b = z; am = 4; }
            z = zr[(hi >> 8) & 63];  if (z > b) { b = z; am = 5; }
            z = zr[(hi >> 16) & 63]; if (z > b) { b = z; am = 6; }
            z = zr[hi >> 24];        if (z > b) { b = z; am = 7; }
            const unsigned cb = (unsigned)c;
            if (am < 4) { const int sh = am * 8; lo = (lo & ~(255u << sh)) | (cb << sh); }
            else        { const int sh = am * 8 - 32; hi = (hi & ~(255u << sh)) | (cb << sh); }
        }
    } else {
        const int t2 = tid - 64;  // 0..191
        const float4* b1s = (const float4*)(wsc + WSB_B1);
        float4* b1d = (float4*)sB1;
        for (int i = t2; i < 1344; i += 192) b1d[i] = b1s[i];
        const float4* w2s = (const float4*)(wsc + WSB_W2);
        float4* w2d = (float4*)sW2;
        for (int i = t2; i < 576; i += 192) w2d[i] = w2s[i];
        const float4 z4 = {0.f, 0.f, 0.f, 0.f};
        float4* ad = (float4*)sA;
        for (int i = t2; i < 1344; i += 192) ad[i] = z4;
    }
    __syncthreads();

    // ---- phase 2: build A = [counts64 | onehot66(q)] (row threads) ----
    if (tid < 64) {
        int t_[8] = { (int)(lo & 63), (int)((lo >> 8) & 63), (int)((lo >> 16) & 63), (int)(lo >> 24),
                      (int)(hi & 63), (int)((hi >> 8) & 63), (int)((hi >> 16) & 63), (int)(hi >> 24) };
        int tot[8] = {1, 1, 1, 1, 1, 1, 1, 1};
        #pragma unroll
        for (int i = 0; i < 8; ++i)
            #pragma unroll
            for (int j = i + 1; j < 8; ++j) {
                const int eq = (t_[i] == t_[j]);
                tot[i] += eq; tot[j] += eq;
            }
        _Float16* arow = sA + tid * 168;
        #pragma unroll
        for (int i = 0; i < 8; ++i) arow[t_[i]] = (_Float16)(float)tot[i];
        arow[64 + qt] = (_Float16)1.0f;
    }
    __syncthreads();

    // ---- phase 3: MFMA-1  h256 = A @ B1  (K=160), relu -> sH fp16 ----
    const int lane = tid & 63;
    const int w = tid >> 6;
    const int c16 = lane & 15, g = lane >> 4;
    const int arow = w * 16 + c16;
    f32x4 a0 = {0.f, 0.f, 0.f, 0.f}, a1 = a0, a2 = a0, a3 = a0;
    #pragma unroll
    for (int ks = 0; ks < 5; ++ks) {
        const int ko = ks * 32 + g * 8;
        const f16x8 af = *(const f16x8*)&sA[arow * 168 + ko];
        const f16x8 b0 = *(const f16x8*)&sB1[(c16) * 168 + ko];
        const f16x8 b1 = *(const f16x8*)&sB1[(16 + c16) * 168 + ko];
        const f16x8 b2 = *(const f16x8*)&sB1[(32 + c16) * 168 + ko];
        const f16x8 b3 = *(const f16x8*)&sB1[(48 + c16) * 168 + ko];
        a0 = __builtin_amdgcn_mfma_f32_16x16x32_f16(af, b0, a0, 0, 0, 0);
        a1 = __builtin_amdgcn_mfma_f32_16x16x32_f16(af, b1, a1, 0, 0, 0);
        a2 = __builtin_amdgcn_mfma_f32_16x16x32_f16(af, b2, a2, 0, 0, 0);
        a3 = __builtin_amdgcn_mfma_f32_16x16x32_f16(af, b3, a3, 0, 0, 0);
    }
    {
        const int rbase = w * 16 + g * 4;
        #pragma unroll
        for (int j = 0; j < 4; ++j) {
            _Float16* hr = sH + (rbase + j) * 72;
            const float v0 = a0[j], v1 = a1[j], v2 = a2[j], v3 = a3[j];
            hr[c16]      = (_Float16)(v0 > 0.f ? v0 : 0.f);
            hr[16 + c16] = (_Float16)(v1 > 0.f ? v1 : 0.f);
            hr[32 + c16] = (_Float16)(v2 > 0.f ? v2 : 0.f);
            hr[48 + c16] = (_Float16)(v3 > 0.f ? v3 : 0.f);
        }
    }
    __syncthreads();

    // ---- phase 4: MFMA-2  logits256 = relu(h256) @ W2t  (K=64) ----
    f32x4 d0 = {0.f, 0.f, 0.f, 0.f}, d1 = d0, d2 = d0, d3 = d0;
    #pragma unroll
    for (int ks = 0; ks < 2; ++ks) {
        const int ko = ks * 32 + g * 8;
        const f16x8 af = *(const f16x8*)&sH[arow * 72 + ko];
        const f16x8 b0 = *(const f16x8*)&sW2[(c16) * 72 + ko];
        const f16x8 b1 = *(const f16x8*)&sW2[(16 + c16) * 72 + ko];
        const f16x8 b2 = *(const f16x8*)&sW2[(32 + c16) * 72 + ko];
        const f16x8 b3 = *(const f16x8*)&sW2[(48 + c16) * 72 + ko];
        d0 = __builtin_amdgcn_mfma_f32_16x16x32_f16(af, b0, d0, 0, 0, 0);
        d1 = __builtin_amdgcn_mfma_f32_16x16x32_f16(af, b1, d1, 0, 0, 0);
        d2 = __builtin_amdgcn_mfma_f32_16x16x32_f16(af, b2, d2, 0, 0, 0);
        d3 = __builtin_amdgcn_mfma_f32_16x16x32_f16(af, b3, d3, 0, 0, 0);
    }
    float* sOut = (float*)(void*)sA;  // reuse sA region: [64][68] f32
    {
        const int rbase = w * 16 + g * 4;
        #pragma unroll
        for (int j = 0; j < 4; ++j) {
            float* orow = sOut + (rbase + j) * 68;
            orow[c16]      = d0[j] * (1.f / 256.f) + sRb2[c16];
            orow[16 + c16] = d1[j] * (1.f / 256.f) + sRb2[16 + c16];
            orow[32 + c16] = d2[j] * (1.f / 256.f) + sRb2[32 + c16];
            orow[48 + c16] = d3[j] * (1.f / 256.f) + sRb2[48 + c16];
        }
    }
    __syncthreads();

    // ---- phase 5: coalesced store ----
    #pragma unroll
    for (int r2 = 0; r2 < 4; ++r2) {
        const int idx = r2 * 256 + tid;
        const int row = idx >> 4, c4 = idx & 15;
        *(float4*)(out + (size_t)(base + row) * 64 + c4 * 4) =
            *(const float4*)&sOut[row * 68 + c4 * 4];
    }
}

extern "C" void kernel_launch(void* const* d_in, const int* in_sizes, int n_in,
                              void* d_out, int out_size, void* d_ws, size_t ws_size,
                              hipStream_t stream)
{
    const int* seqs    = (const int*)d_in[0];
    const int* qtok    = (const int*)d_in[1];
    const float* embed = (const float*)d_in[2];
    const float* gw1   = (const float*)d_in[3];
    const float* gb1   = (const float*)d_in[4];
    const float* gw2   = (const float*)d_in[5];
    const float* gb2   = (const float*)d_in[6];
    const float* rw1   = (const float*)d_in[7];
    const float* rb1   = (const float*)d_in[8];
    const float* rw2   = (const float*)d_in[9];
    const float* rb2   = (const float*)d_in[10];
    char* wsc  = (char*)d_ws;
    float* out = (float*)d_out;
    const int B = in_sizes[1];

    sm_precompute<<<66, 256, 0, stream>>>(embed, gw1, gb1, gw2, gb2, rw1, rb1, rw2, wsc);
    sm_main<<<B / 64, 256, 0, stream>>>(seqs, qtok, rb2, wsc, out);
}

// Round 3
// 23.217 us; speedup vs baseline: 2.3601x; 2.3601x over previous
//
#include <hip/hip_runtime.h>
#include <math.h>

typedef __attribute__((ext_vector_type(8))) _Float16 f16x8;
typedef __attribute__((ext_vector_type(4))) float f32x4;

#define TSTEPS 23

// ws byte offsets
#define WSB_Z  0        // [64][64] f32 sigmoid LUT (16384 B)
#define WSB_B1 16384    // [64 n][168 k] f16 combined table *256 (21504 B)
#define WSB_W2 37888    // [64 n][72 k] f16 rw2 transposed (9216 B)
#define WSB_U  47104    // [64 c][32 j] f32 ctx gate proj (8192 B)
#define WSB_V  55296    // [64 s][32 j] f32 mem gate proj (8192 B)

// ---- stage 1: all matmul-shaped tables, one output per thread, LDS-fed ----
__global__ __launch_bounds__(256) void pre_tables(
    const float* __restrict__ embed, const float* __restrict__ gw1,
    const float* __restrict__ rw1, const float* __restrict__ rb1,
    const float* __restrict__ rw2, char* __restrict__ wsc)
{
    __shared__ float sEmb[66 * 64];   // 16896 B
    __shared__ float sW[128 * 64];    // 32768 B (gw1 as [128][32] or rw1 as [128][64])
    __shared__ float sRb1[64];

    const int tid = threadIdx.x;
    const int blk = blockIdx.x;

    if (blk < 16) {
        // ---- u/v gate projections: 4096 outputs, 1/thread ----
        {
            const float4* es = (const float4*)embed;
            float4* ed = (float4*)sEmb;
            for (int i = tid; i < 1056; i += 256) ed[i] = es[i];
            const float4* gs = (const float4*)gw1;       // [128][32] = 1024 f4
            float4* gd = (float4*)sW;
            for (int i = tid; i < 1024; i += 256) gd[i] = gs[i];
        }
        __syncthreads();
        const int e = blk * 256 + tid;                   // 0..4095
        const int row = (e >> 5) & 63, j = e & 31;
        const int ofs = (e < 2048) ? 0 : 64;             // ctx uses gw1[0:64], mem gw1[64:128]
        float acc = 0.f;
        const float* er = sEmb + row * 64;
        #pragma unroll
        for (int k = 0; k < 64; ++k)
            acc = fmaf(er[k], sW[(ofs + k) * 32 + j], acc);
        float* dst = (float*)(wsc + ((e < 2048) ? WSB_U : WSB_V));
        dst[e & 2047] = acc;
    } else if (blk < 49) {
        // ---- B1 combined table: 8320 outputs, 1/thread ----
        {
            const float4* es = (const float4*)embed;
            float4* ed = (float4*)sEmb;
            for (int i = tid; i < 1056; i += 256) ed[i] = es[i];
            const float4* rs = (const float4*)rw1;       // [128][64] = 2048 f4
            float4* rd = (float4*)sW;
            for (int i = tid; i < 2048; i += 256) rd[i] = rs[i];
            if (tid < 64) sRb1[tid] = rb1[tid];
        }
        __syncthreads();
        const int e = (blk - 16) * 256 + tid;
        if (e < 8320) {
            const int n = e & 63, k = e >> 6;            // k < 130
            float acc;
            if (k < 64) {                                // counts side (mem half of rw1)
                acc = 0.f;
                const float* er = sEmb + k * 64;
                #pragma unroll
                for (int m = 0; m < 64; ++m)
                    acc = fmaf(er[m], sW[(64 + m) * 64 + n], acc);
                acc *= 0.125f * 256.f;
            } else {                                     // query side (ctx half, incl rb1)
                const int t = k - 64;
                acc = sRb1[n];
                const float* er = sEmb + t * 64;
                #pragma unroll
                for (int m = 0; m < 64; ++m)
                    acc = fmaf(er[m], sW[m * 64 + n], acc);
                acc *= 256.f;
            }
            ((_Float16*)(wsc + WSB_B1))[n * 168 + k] = (_Float16)acc;
        }
    } else {
        // ---- W2 transpose + B1 k-pads ----
        _Float16* w2t = (_Float16*)(wsc + WSB_W2);
        for (int e = tid; e < 4096; e += 256) {
            const int n = e & 63, j = e >> 6;
            w2t[n * 72 + j] = (_Float16)rw2[j * 64 + n];
        }
        _Float16* b1 = (_Float16*)(wsc + WSB_B1);
        for (int e = tid; e < 2432; e += 256) {          // k in [130,168)
            const int n = e / 38, k = 130 + (e - n * 38);
            b1[n * 168 + k] = (_Float16)0.f;
        }
    }
}

// ---- stage 2: Z table double-precision finisher (bitwise = round-1 path) ----
__global__ __launch_bounds__(256) void pre_z(
    const float* __restrict__ gb1, const float* __restrict__ gw2,
    const float* __restrict__ gb2, char* __restrict__ wsc)
{
    __shared__ float sU[64 * 33];
    __shared__ float sV[64 * 33];
    __shared__ float sG1[32];
    __shared__ float sG2[32];

    const int tid = threadIdx.x;
    const float* u = (const float*)(wsc + WSB_U);
    const float* v = (const float*)(wsc + WSB_V);
    for (int i = tid; i < 2048; i += 256) {
        sU[(i >> 5) * 33 + (i & 31)] = u[i];
        sV[(i >> 5) * 33 + (i & 31)] = v[i];
    }
    if (tid < 32) { sG1[tid] = gb1[tid]; sG2[tid] = gw2[tid]; }
    __syncthreads();

    const int idx = blockIdx.x * 256 + tid;              // 0..4095
    const int c = idx >> 6, s = idx & 63;
    double z = (double)gb2[0];
    #pragma unroll
    for (int j = 0; j < 32; ++j) {
        const double a = (double)sU[c * 33 + j] + (double)sV[s * 33 + j] + (double)sG1[j];
        if (a > 0.0) z += a * (double)sG2[j];
    }
    ((float*)(wsc + WSB_Z))[idx] = (float)(1.0 / (1.0 + exp(-z)));
}

__global__ __launch_bounds__(256, 2) void sm_main(
    const int* __restrict__ seqs, const int* __restrict__ qtok,
    const float* __restrict__ rb2, const char* __restrict__ wsc,
    float* __restrict__ out)
{
    __shared__ __align__(16) float     sZ[64 * 64];
    __shared__ __align__(16) _Float16  sB1[64 * 168];
    __shared__ __align__(16) _Float16  sA[64 * 168];   // reused as sOut f32 [64][68]
    __shared__ __align__(16) _Float16  sW2[64 * 72];
    __shared__ __align__(16) _Float16  sH[64 * 72];
    __shared__ unsigned sTokPk[64 * 6];
    __shared__ float sRb2[64];

    const int tid = threadIdx.x;
    const int base = blockIdx.x * 64;

    // ---- phase 0: stage Z + tokens (all threads) ----
    {
        const float4* zsrc = (const float4*)(wsc + WSB_Z);
        float4* zdst = (float4*)sZ;
        for (int i = tid; i < 1024; i += 256) zdst[i] = zsrc[i];
        const int4* sq = (const int4*)(seqs + base * 24);
        for (int g = tid; g < 384; g += 256) {
            const int4 w = sq[g];
            sTokPk[g] = (unsigned)w.x | ((unsigned)w.y << 8) |
                        ((unsigned)w.z << 16) | ((unsigned)w.w << 24);
        }
        if (tid < 64) sRb2[tid] = rb2[tid];
    }
    int qt = 0;
    if (tid < 64) qt = qtok[base + tid];
    __syncthreads();

    // ---- phase 1: wave0 scans; waves 1-3 stage B1/W2 and zero A ----
    unsigned lo = 0, hi = 0;
    if (tid < 64) {
        const unsigned char* tk = ((const unsigned char*)sTokPk) + tid * 24;
        lo = sTokPk[tid * 6 + 0];
        hi = sTokPk[tid * 6 + 1];
        #pragma unroll
        for (int t = 8; t < TSTEPS; ++t) {
            const int c = tk[t];
            const float* zr = sZ + c * 64;
            float b = zr[lo & 63]; int am = 0; float z;
            z = zr[(lo >> 8) & 63];  if (z > b) { b = z; am = 1; }
            z = zr[(lo >> 16) & 63]; if (z > b) { b = z; am = 2; }
            z = zr[lo >> 24];        if (z > b) { b = z; am = 3; }
            z = zr[hi & 63];         if (z > b) { b = z; am = 4; }
            z = zr[(hi >> 8) & 63];  if (z > b) { b = z; am = 5; }
            z = zr[(hi >> 16) & 63]; if (z > b) { b = z; am = 6; }
            z = zr[hi >> 24];        if (z > b) { b = z; am = 7; }
            const unsigned cb = (unsigned)c;
            if (am < 4) { const int sh = am * 8; lo = (lo & ~(255u << sh)) | (cb << sh); }
            else        { const int sh = am * 8 - 32; hi = (hi & ~(255u << sh)) | (cb << sh); }
        }
    } else {
        const int t2 = tid - 64;  // 0..191
        const float4* b1s = (const float4*)(wsc + WSB_B1);
        float4* b1d = (float4*)sB1;
        for (int i = t2; i < 1344; i += 192) b1d[i] = b1s[i];
        const float4* w2s = (const float4*)(wsc + WSB_W2);
        float4* w2d = (float4*)sW2;
        for (int i = t2; i < 576; i += 192) w2d[i] = w2s[i];
        const float4 z4 = {0.f, 0.f, 0.f, 0.f};
        float4* ad = (float4*)sA;
        for (int i = t2; i < 1344; i += 192) ad[i] = z4;
    }
    __syncthreads();

    // ---- phase 2: build A = [counts64 | onehot66(q)] (row threads) ----
    if (tid < 64) {
        int t_[8] = { (int)(lo & 63), (int)((lo >> 8) & 63), (int)((lo >> 16) & 63), (int)(lo >> 24),
                      (int)(hi & 63), (int)((hi >> 8) & 63), (int)((hi >> 16) & 63), (int)(hi >> 24) };
        int tot[8] = {1, 1, 1, 1, 1, 1, 1, 1};
        #pragma unroll
        for (int i = 0; i < 8; ++i)
            #pragma unroll
            for (int j = i + 1; j < 8; ++j) {
                const int eq = (t_[i] == t_[j]);
                tot[i] += eq; tot[j] += eq;
            }
        _Float16* arow = sA + tid * 168;
        #pragma unroll
        for (int i = 0; i < 8; ++i) arow[t_[i]] = (_Float16)(float)tot[i];
        arow[64 + qt] = (_Float16)1.0f;
    }
    __syncthreads();

    // ---- phase 3: MFMA-1  h256 = A @ B1  (K=160), relu -> sH fp16 ----
    const int lane = tid & 63;
    const int w = tid >> 6;
    const int c16 = lane & 15, g = lane >> 4;
    const int arow = w * 16 + c16;
    f32x4 a0 = {0.f, 0.f, 0.f, 0.f}, a1 = a0, a2 = a0, a3 = a0;
    #pragma unroll
    for (int ks = 0; ks < 5; ++ks) {
        const int ko = ks * 32 + g * 8;
        const f16x8 af = *(const f16x8*)&sA[arow * 168 + ko];
        const f16x8 b0 = *(const f16x8*)&sB1[(c16) * 168 + ko];
        const f16x8 b1 = *(const f16x8*)&sB1[(16 + c16) * 168 + ko];
        const f16x8 b2 = *(const f16x8*)&sB1[(32 + c16) * 168 + ko];
        const f16x8 b3 = *(const f16x8*)&sB1[(48 + c16) * 168 + ko];
        a0 = __builtin_amdgcn_mfma_f32_16x16x32_f16(af, b0, a0, 0, 0, 0);
        a1 = __builtin_amdgcn_mfma_f32_16x16x32_f16(af, b1, a1, 0, 0, 0);
        a2 = __builtin_amdgcn_mfma_f32_16x16x32_f16(af, b2, a2, 0, 0, 0);
        a3 = __builtin_amdgcn_mfma_f32_16x16x32_f16(af, b3, a3, 0, 0, 0);
    }
    {
        const int rbase = w * 16 + g * 4;
        #pragma unroll
        for (int j = 0; j < 4; ++j) {
            _Float16* hr = sH + (rbase + j) * 72;
            const float v0 = a0[j], v1 = a1[j], v2 = a2[j], v3 = a3[j];
            hr[c16]      = (_Float16)(v0 > 0.f ? v0 : 0.f);
            hr[16 + c16] = (_Float16)(v1 > 0.f ? v1 : 0.f);
            hr[32 + c16] = (_Float16)(v2 > 0.f ? v2 : 0.f);
            hr[48 + c16] = (_Float16)(v3 > 0.f ? v3 : 0.f);
        }
    }
    __syncthreads();

    // ---- phase 4: MFMA-2  logits256 = relu(h256) @ W2t  (K=64) ----
    f32x4 d0 = {0.f, 0.f, 0.f, 0.f}, d1 = d0, d2 = d0, d3 = d0;
    #pragma unroll
    for (int ks = 0; ks < 2; ++ks) {
        const int ko = ks * 32 + g * 8;
        const f16x8 af = *(const f16x8*)&sH[arow * 72 + ko];
        const f16x8 b0 = *(const f16x8*)&sW2[(c16) * 72 + ko];
        const f16x8 b1 = *(const f16x8*)&sW2[(16 + c16) * 72 + ko];
        const f16x8 b2 = *(const f16x8*)&sW2[(32 + c16) * 72 + ko];
        const f16x8 b3 = *(const f16x8*)&sW2[(48 + c16) * 72 + ko];
        d0 = __builtin_amdgcn_mfma_f32_16x16x32_f16(af, b0, d0, 0, 0, 0);
        d1 = __builtin_amdgcn_mfma_f32_16x16x32_f16(af, b1, d1, 0, 0, 0);
        d2 = __builtin_amdgcn_mfma_f32_16x16x32_f16(af, b2, d2, 0, 0, 0);
        d3 = __builtin_amdgcn_mfma_f32_16x16x32_f16(af, b3, d3, 0, 0, 0);
    }
    float* sOut = (float*)(void*)sA;  // reuse sA region: [64][68] f32
    {
        const int rbase = w * 16 + g * 4;
        #pragma unroll
        for (int j = 0; j < 4; ++j) {
            float* orow = sOut + (rbase + j) * 68;
            orow[c16]      = d0[j] * (1.f / 256.f) + sRb2[c16];
            orow[16 + c16] = d1[j] * (1.f / 256.f) + sRb2[16 + c16];
            orow[32 + c16] = d2[j] * (1.f / 256.f) + sRb2[32 + c16];
            orow[48 + c16] = d3[j] * (1.f / 256.f) + sRb2[48 + c16];
        }
    }
    __syncthreads();

    // ---- phase 5: coalesced store ----
    #pragma unroll
    for (int r2 = 0; r2 < 4; ++r2) {
        const int idx = r2 * 256 + tid;
        const int row = idx >> 4, c4 = idx & 15;
        *(float4*)(out + (size_t)(base + row) * 64 + c4 * 4) =
            *(const float4*)&sOut[row * 68 + c4 * 4];
    }
}

extern "C" void kernel_launch(void* const* d_in, const int* in_sizes, int n_in,
                              void* d_out, int out_size, void* d_ws, size_t ws_size,
                              hipStream_t stream)
{
    const int* seqs    = (const int*)d_in[0];
    const int* qtok    = (const int*)d_in[1];
    const float* embed = (const float*)d_in[2];
    const float* gw1   = (const float*)d_in[3];
    const float* gb1   = (const float*)d_in[4];
    const float* gw2   = (const float*)d_in[5];
    const float* gb2   = (const float*)d_in[6];
    const float* rw1   = (const float*)d_in[7];
    const float* rb1   = (const float*)d_in[8];
    const float* rw2   = (const float*)d_in[9];
    const float* rb2   = (const float*)d_in[10];
    char* wsc  = (char*)d_ws;
    float* out = (float*)d_out;
    const int B = in_sizes[1];

    pre_tables<<<50, 256, 0, stream>>>(embed, gw1, rw1, rb1, rw2, wsc);
    pre_z<<<16, 256, 0, stream>>>(gb1, gw2, gb2, wsc);
    sm_main<<<B / 64, 256, 0, stream>>>(seqs, qtok, rb2, wsc, out);
}

// Round 4
// 22.815 us; speedup vs baseline: 2.4016x; 1.0176x over previous
//
#include <hip/hip_runtime.h>
#include <math.h>

typedef __attribute__((ext_vector_type(8))) _Float16 f16x8;
typedef __attribute__((ext_vector_type(4))) float f32x4;

#define TSTEPS 23

// ws byte offsets
#define WSB_Z  0        // [64][64] f32 sigmoid LUT (16384 B)
#define WSB_B1 16384    // [64 n][168 k] f16 combined table *256 (21504 B)
#define WSB_W2 37888    // [64 n][72 k] f16 rw2 transposed (9216 B)

// ---- single precompute kernel: Z (blocks 0-15), B1 (16-48), W2 (49) ----
__global__ __launch_bounds__(256) void pre_all(
    const float* __restrict__ embed, const float* __restrict__ gw1,
    const float* __restrict__ gb1, const float* __restrict__ gw2,
    const float* __restrict__ gb2, const float* __restrict__ rw1,
    const float* __restrict__ rb1, const float* __restrict__ rw2,
    char* __restrict__ wsc)
{
    __shared__ float sEmb[66 * 64];   // 16896 B
    __shared__ float sW[128 * 64];    // 32768 B
    __shared__ float sV[64 * 33];     // 8448 B (padded)
    __shared__ float sU[4 * 32];
    __shared__ float sG[65];          // gb1[0:32], gw2[32:64], gb2[64]
    __shared__ float sRb1[64];

    const int tid = threadIdx.x;
    const int blk = blockIdx.x;

    if (blk < 16) {
        // ---- Z rows c in [blk*4, blk*4+4): v computed redundantly in LDS ----
        {
            const float4* es = (const float4*)embed;
            float4* ed = (float4*)sEmb;
            for (int i = tid; i < 1024; i += 256) ed[i] = es[i];
            const float4* gs = (const float4*)gw1;       // [128][32]
            float4* gd = (float4*)sW;
            for (int i = tid; i < 1024; i += 256) gd[i] = gs[i];
            if (tid < 32) { sG[tid] = gb1[tid]; sG[32 + tid] = gw2[tid]; }
            if (tid == 64) sG[64] = gb2[0];
        }
        __syncthreads();
        #pragma unroll
        for (int i = 0; i < 8; ++i) {                    // full v: 64 s × 32 j
            const int e = tid + i * 256;
            const int s = e >> 5, j = e & 31;
            float acc = 0.f;
            const float* er = sEmb + s * 64;
            #pragma unroll
            for (int k = 0; k < 64; ++k)
                acc = fmaf(er[k], sW[(64 + k) * 32 + j], acc);
            sV[s * 33 + j] = acc;
        }
        if (tid < 128) {                                 // u: 4 c-rows × 32 j
            const int cc = tid >> 5, j = tid & 31;
            const int c = blk * 4 + cc;
            float acc = 0.f;
            const float* er = sEmb + c * 64;
            #pragma unroll
            for (int k = 0; k < 64; ++k)
                acc = fmaf(er[k], sW[k * 32 + j], acc);
            sU[cc * 32 + j] = acc;
        }
        __syncthreads();
        const int cc = tid >> 6, s = tid & 63;           // DP finisher, 1/thread
        const int c = blk * 4 + cc;
        double z = (double)sG[64];
        #pragma unroll
        for (int j = 0; j < 32; ++j) {
            const double a = (double)sU[cc * 32 + j] + (double)sV[s * 33 + j] + (double)sG[j];
            if (a > 0.0) z += a * (double)sG[32 + j];
        }
        ((float*)(wsc + WSB_Z))[c * 64 + s] = (float)(1.0 / (1.0 + exp(-z)));
    } else if (blk < 49) {
        // ---- B1 combined table: 8320 outputs, 1/thread ----
        {
            const float4* es = (const float4*)embed;
            float4* ed = (float4*)sEmb;
            for (int i = tid; i < 1056; i += 256) ed[i] = es[i];
            const float4* rs = (const float4*)rw1;       // [128][64]
            float4* rd = (float4*)sW;
            for (int i = tid; i < 2048; i += 256) rd[i] = rs[i];
            if (tid < 64) sRb1[tid] = rb1[tid];
        }
        __syncthreads();
        const int e = (blk - 16) * 256 + tid;
        if (e < 8320) {
            const int n = e & 63, k = e >> 6;            // k < 130
            float acc;
            if (k < 64) {                                // counts side (mem half)
                acc = 0.f;
                const float* er = sEmb + k * 64;
                #pragma unroll
                for (int m = 0; m < 64; ++m)
                    acc = fmaf(er[m], sW[(64 + m) * 64 + n], acc);
                acc *= 0.125f * 256.f;
            } else {                                     // query side (ctx half + rb1)
                const int t = k - 64;
                acc = sRb1[n];
                const float* er = sEmb + t * 64;
                #pragma unroll
                for (int m = 0; m < 64; ++m)
                    acc = fmaf(er[m], sW[m * 64 + n], acc);
                acc *= 256.f;
            }
            ((_Float16*)(wsc + WSB_B1))[n * 168 + k] = (_Float16)acc;
        }
    } else {
        // ---- W2 transpose + B1 k-pads ----
        _Float16* w2t = (_Float16*)(wsc + WSB_W2);
        for (int e = tid; e < 4096; e += 256) {
            const int n = e & 63, j = e >> 6;
            w2t[n * 72 + j] = (_Float16)rw2[j * 64 + n];
        }
        _Float16* b1 = (_Float16*)(wsc + WSB_B1);
        for (int e = tid; e < 2432; e += 256) {          // k in [130,168)
            const int n = e / 38, k = 130 + (e - n * 38);
            b1[n * 168 + k] = (_Float16)0.f;
        }
    }
}

#define ROWS 128

__global__ __launch_bounds__(512, 2) void sm_main(
    const int* __restrict__ seqs, const int* __restrict__ qtok,
    const float* __restrict__ rb2, const char* __restrict__ wsc,
    float* __restrict__ out)
{
    __shared__ __align__(16) float     sZ[64 * 64];     // 16384
    __shared__ __align__(16) _Float16  sB1[64 * 168];   // 21504
    __shared__ __align__(16) _Float16  sA[128 * 168];   // 43008, reused as sOut f32 [128][68]
    __shared__ __align__(16) _Float16  sW2[64 * 72];    // 9216
    __shared__ __align__(16) _Float16  sH[128 * 72];    // 18432
    __shared__ float sRb2[64];

    const int tid = threadIdx.x;
    const int base = blockIdx.x * ROWS;

    // ---- issue token loads early (latency hides under table staging) ----
    unsigned pk[6];
    int qt = 0;
    if (tid < ROWS) {
        const int4* sq = (const int4*)(seqs + (size_t)(base + tid) * 24);
        #pragma unroll
        for (int i = 0; i < 6; ++i) {
            const int4 w4 = sq[i];
            pk[i] = (unsigned)w4.x | ((unsigned)w4.y << 8) |
                    ((unsigned)w4.z << 16) | ((unsigned)w4.w << 24);
        }
        qt = qtok[base + tid];
    }

    // ---- stage tables + zero A ----
    {
        const float4* zsrc = (const float4*)(wsc + WSB_Z);
        float4* zdst = (float4*)sZ;
        for (int i = tid; i < 1024; i += 512) zdst[i] = zsrc[i];
        const float4* b1s = (const float4*)(wsc + WSB_B1);
        float4* b1d = (float4*)sB1;
        for (int i = tid; i < 1344; i += 512) b1d[i] = b1s[i];
        const float4* w2s = (const float4*)(wsc + WSB_W2);
        float4* w2d = (float4*)sW2;
        for (int i = tid; i < 576; i += 512) w2d[i] = w2s[i];
        const float4 z4 = {0.f, 0.f, 0.f, 0.f};
        float4* ad = (float4*)sA;
        for (int i = tid; i < 2688; i += 512) ad[i] = z4;
        if (tid < 64) sRb2[tid] = rb2[tid];
    }
    __syncthreads();

    // ---- scan + A build (threads 0-127, waves 0-1) ----
    if (tid < ROWS) {
        unsigned lo = pk[0], hi = pk[1];
        #pragma unroll
        for (int t = 8; t < TSTEPS; ++t) {
            const int c = (int)((pk[t >> 2] >> ((t & 3) * 8)) & 255u);
            const float* zr = sZ + c * 64;
            float b = zr[lo & 63]; int am = 0; float z;
            z = zr[(lo >> 8) & 63];  if (z > b) { b = z; am = 1; }
            z = zr[(lo >> 16) & 63]; if (z > b) { b = z; am = 2; }
            z = zr[lo >> 24];        if (z > b) { b = z; am = 3; }
            z = zr[hi & 63];         if (z > b) { b = z; am = 4; }
            z = zr[(hi >> 8) & 63];  if (z > b) { b = z; am = 5; }
            z = zr[(hi >> 16) & 63]; if (z > b) { b = z; am = 6; }
            z = zr[hi >> 24];        if (z > b) { b = z; am = 7; }
            const unsigned cb = (unsigned)c;
            if (am < 4) { const int sh = am * 8; lo = (lo & ~(255u << sh)) | (cb << sh); }
            else        { const int sh = am * 8 - 32; hi = (hi & ~(255u << sh)) | (cb << sh); }
        }
        int t_[8] = { (int)(lo & 63), (int)((lo >> 8) & 63), (int)((lo >> 16) & 63), (int)(lo >> 24),
                      (int)(hi & 63), (int)((hi >> 8) & 63), (int)((hi >> 16) & 63), (int)(hi >> 24) };
        int tot[8] = {1, 1, 1, 1, 1, 1, 1, 1};
        #pragma unroll
        for (int i = 0; i < 8; ++i)
            #pragma unroll
            for (int j = i + 1; j < 8; ++j) {
                const int eq = (t_[i] == t_[j]);
                tot[i] += eq; tot[j] += eq;
            }
        _Float16* arow = sA + tid * 168;
        #pragma unroll
        for (int i = 0; i < 8; ++i) arow[t_[i]] = (_Float16)(float)tot[i];
        arow[64 + qt] = (_Float16)1.0f;
    }
    __syncthreads();

    // ---- MFMA-1: h = A @ B1 (K=160), relu -> sH fp16 ----
    const int lane = tid & 63;
    const int w = tid >> 6;                 // 0..7
    const int c16 = lane & 15, g = lane >> 4;
    const int arow = w * 16 + c16;          // 0..127
    f32x4 a0 = {0.f, 0.f, 0.f, 0.f}, a1 = a0, a2 = a0, a3 = a0;
    #pragma unroll
    for (int ks = 0; ks < 5; ++ks) {
        const int ko = ks * 32 + g * 8;
        const f16x8 af = *(const f16x8*)&sA[arow * 168 + ko];
        const f16x8 b0 = *(const f16x8*)&sB1[(c16) * 168 + ko];
        const f16x8 b1 = *(const f16x8*)&sB1[(16 + c16) * 168 + ko];
        const f16x8 b2 = *(const f16x8*)&sB1[(32 + c16) * 168 + ko];
        const f16x8 b3 = *(const f16x8*)&sB1[(48 + c16) * 168 + ko];
        a0 = __builtin_amdgcn_mfma_f32_16x16x32_f16(af, b0, a0, 0, 0, 0);
        a1 = __builtin_amdgcn_mfma_f32_16x16x32_f16(af, b1, a1, 0, 0, 0);
        a2 = __builtin_amdgcn_mfma_f32_16x16x32_f16(af, b2, a2, 0, 0, 0);
        a3 = __builtin_amdgcn_mfma_f32_16x16x32_f16(af, b3, a3, 0, 0, 0);
    }
    {
        const int rbase = w * 16 + g * 4;
        #pragma unroll
        for (int j = 0; j < 4; ++j) {
            _Float16* hr = sH + (rbase + j) * 72;
            const float v0 = a0[j], v1 = a1[j], v2 = a2[j], v3 = a3[j];
            hr[c16]      = (_Float16)(v0 > 0.f ? v0 : 0.f);
            hr[16 + c16] = (_Float16)(v1 > 0.f ? v1 : 0.f);
            hr[32 + c16] = (_Float16)(v2 > 0.f ? v2 : 0.f);
            hr[48 + c16] = (_Float16)(v3 > 0.f ? v3 : 0.f);
        }
    }
    __syncthreads();

    // ---- MFMA-2: logits = relu(h) @ W2t (K=64) ----
    f32x4 d0 = {0.f, 0.f, 0.f, 0.f}, d1 = d0, d2 = d0, d3 = d0;
    #pragma unroll
    for (int ks = 0; ks < 2; ++ks) {
        const int ko = ks * 32 + g * 8;
        const f16x8 af = *(const f16x8*)&sH[arow * 72 + ko];
        const f16x8 b0 = *(const f16x8*)&sW2[(c16) * 72 + ko];
        const f16x8 b1 = *(const f16x8*)&sW2[(16 + c16) * 72 + ko];
        const f16x8 b2 = *(const f16x8*)&sW2[(32 + c16) * 72 + ko];
        const f16x8 b3 = *(const f16x8*)&sW2[(48 + c16) * 72 + ko];
        d0 = __builtin_amdgcn_mfma_f32_16x16x32_f16(af, b0, d0, 0, 0, 0);
        d1 = __builtin_amdgcn_mfma_f32_16x16x32_f16(af, b1, d1, 0, 0, 0);
        d2 = __builtin_amdgcn_mfma_f32_16x16x32_f16(af, b2, d2, 0, 0, 0);
        d3 = __builtin_amdgcn_mfma_f32_16x16x32_f16(af, b3, d3, 0, 0, 0);
    }
    float* sOut = (float*)(void*)sA;        // reuse sA: [128][68] f32
    {
        const int rbase = w * 16 + g * 4;
        #pragma unroll
        for (int j = 0; j < 4; ++j) {
            float* orow = sOut + (rbase + j) * 68;
            orow[c16]      = d0[j] * (1.f / 256.f) + sRb2[c16];
            orow[16 + c16] = d1[j] * (1.f / 256.f) + sRb2[16 + c16];
            orow[32 + c16] = d2[j] * (1.f / 256.f) + sRb2[32 + c16];
            orow[48 + c16] = d3[j] * (1.f / 256.f) + sRb2[48 + c16];
        }
    }
    __syncthreads();

    // ---- coalesced store: 128 rows × 64 f32 ----
    #pragma unroll
    for (int r2 = 0; r2 < 4; ++r2) {
        const int idx = r2 * 512 + tid;
        const int row = idx >> 4, c4 = idx & 15;
        *(float4*)(out + (size_t)(base + row) * 64 + c4 * 4) =
            *(const float4*)&sOut[row * 68 + c4 * 4];
    }
}

extern "C" void kernel_launch(void* const* d_in, const int* in_sizes, int n_in,
                              void* d_out, int out_size, void* d_ws, size_t ws_size,
                              hipStream_t stream)
{
    const int* seqs    = (const int*)d_in[0];
    const int* qtok    = (const int*)d_in[1];
    const float* embed = (const float*)d_in[2];
    const float* gw1   = (const float*)d_in[3];
    const float* gb1   = (const float*)d_in[4];
    const float* gw2   = (const float*)d_in[5];
    const float* gb2   = (const float*)d_in[6];
    const float* rw1   = (const float*)d_in[7];
    const float* rb1   = (const float*)d_in[8];
    const float* rw2   = (const float*)d_in[9];
    const float* rb2   = (const float*)d_in[10];
    char* wsc  = (char*)d_ws;
    float* out = (float*)d_out;
    const int B = in_sizes[1];

    pre_all<<<50, 256, 0, stream>>>(embed, gw1, gb1, gw2, gb2, rw1, rb1, rw2, wsc);
    sm_main<<<B / ROWS, 512, 0, stream>>>(seqs, qtok, rb2, wsc, out);
}